// Round 2
// baseline (640.873 us; speedup 1.0000x reference)
//
#include <hip/hip_runtime.h>
#include <hip/hip_bf16.h>

// Problem constants (fixed by reference setup_inputs)
#define NB 5            // B (cav_num)
#define HW 65536        // 256*256
#define NC 256          // C_V+C_F+C_D
#define LISTCAP 4096    // boundary-bin LDS list capacity (expected ~150-260 items)

// Monotone key: ascending pkey == descending utility. Stable ties broken by pixel idx.
__device__ __forceinline__ unsigned int pkey_of(float u) {
    unsigned int b = __float_as_uint(u);
    unsigned int o = (b & 0x80000000u) ? ~b : (b | 0x80000000u); // ascending in u
    return ~o;                                                   // descending in u
}

__device__ __forceinline__ float budget_per_sample(const int* bp) {
    // Robust to harness passing int32/int64 (150000) or float32 (150000.0f) bits.
    int v = bp[0];
    float f = (v > 0 && v < 100000000) ? (float)v : __int_as_float(v);
    return f / (float)NB;   // 150000/5 = 30000.0 exact
}

// K1: per-pixel best utility/group, priority key, weighted cost histogram.
__global__ void k_prep(const float* __restrict__ util,
                       unsigned int* __restrict__ pkeys,
                       unsigned char* __restrict__ meta,
                       unsigned int* __restrict__ hist) {
    int i = blockIdx.x * blockDim.x + threadIdx.x;
    if (i >= NB * HW) return;
    int b = i >> 16;
    const float* u3 = util + (size_t)i * 3;
    float u0 = u3[0], u1 = u3[1], u2 = u3[2];
    int g = 0; float u = u0;
    if (u1 > u) { u = u1; g = 1; }   // jnp.argmax: first max wins (strict >)
    if (u2 > u) { u = u2; g = 2; }
    bool valid = u > 0.0f;           // PENALTY = 0
    unsigned int pk = pkey_of(u);
    pkeys[i] = pk;
    meta[i] = (unsigned char)(g | (valid ? 4 : 0));
    if (valid) {
        int cost = 4 >> g;           // COSTS = [4,2,1]
        atomicAdd(&hist[(b << 16) | (pk >> 16)], (unsigned int)cost);
    }
}

// K2: per-sample scan of 65536 weighted bins -> crossing bin b*, W(before b*).
__global__ void __launch_bounds__(1024) k_scan(const unsigned int* __restrict__ hist,
                                               const int* __restrict__ budget_ptr,
                                               unsigned int* __restrict__ bstar,
                                               unsigned int* __restrict__ wbefore) {
    int b = blockIdx.x;
    const unsigned int* h = hist + (b << 16);
    float budget = budget_per_sample(budget_ptr);
    int t = threadIdx.x;
    unsigned int s = 0;
    #pragma unroll 4
    for (int j = 0; j < 64; ++j) s += h[t * 64 + j];
    __shared__ unsigned int ls[1024];
    ls[t] = s; __syncthreads();
    // Hillis-Steele inclusive scan
    for (int off = 1; off < 1024; off <<= 1) {
        unsigned int v = (t >= off) ? ls[t - off] : 0u;
        __syncthreads();
        ls[t] += v;
        __syncthreads();
    }
    unsigned int incl = ls[t];
    unsigned int excl = incl - s;
    if ((float)excl <= budget && (float)incl > budget) {
        // crossing is inside this thread's 64-bin range
        unsigned int cum = excl; int bb = t * 64;
        for (int j = 0; j < 64; ++j) {
            unsigned int nc = cum + h[t * 64 + j];
            if ((float)nc > budget) { bb = t * 64 + j; break; }
            cum = nc;
        }
        bstar[b] = (unsigned int)bb;
        wbefore[b] = cum;
    }
    if (t == 1023 && (float)incl <= budget) {
        bstar[b] = 65536u;       // sentinel: budget never exceeded
        wbefore[b] = incl;
    }
}

// K4: phase-1 selection for all pixels (bins < b* accepted if valid; else -1).
__global__ void k_selbase(const unsigned int* __restrict__ pkeys,
                          const unsigned char* __restrict__ meta,
                          const unsigned int* __restrict__ bstar,
                          float* __restrict__ sel,
                          char* __restrict__ sel8) {
    int i = blockIdx.x * blockDim.x + threadIdx.x;
    if (i >= NB * HW) return;
    int b = i >> 16;
    unsigned int bs = bstar[b];
    unsigned int pk = pkeys[i];
    unsigned char m = meta[i];
    bool acc = ((pk >> 16) < bs) && (m & 4);
    sel[i]  = acc ? (float)(m & 3) : -1.0f;
    sel8[i] = acc ? (char)(m & 3) : (char)-1;
}

// K3: exact resolve of crossing bin + tail (<=3 extra accepts). One WG per sample.
__global__ void __launch_bounds__(1024) k_boundary(const unsigned int* __restrict__ pkeys,
                                                   const unsigned char* __restrict__ meta,
                                                   const unsigned int* __restrict__ bstar,
                                                   const unsigned int* __restrict__ wbefore,
                                                   const int* __restrict__ budget_ptr,
                                                   float* __restrict__ sel,
                                                   char* __restrict__ sel8) {
    int b = blockIdx.x;
    unsigned int bs = bstar[b];
    if (bs >= 65536u) return;                 // no crossing: phase-1 covered everything
    float budget = budget_per_sample(budget_ptr);
    __shared__ unsigned long long list[LISTCAP];
    __shared__ unsigned long long red[1024];
    __shared__ unsigned int cnt;
    __shared__ float usage_sh;
    int t = threadIdx.x;
    if (t == 0) cnt = 0;
    __syncthreads();
    const unsigned int* pk_b = pkeys + (b << 16);
    const unsigned char* mt_b = meta + (b << 16);
    // gather valid items of the crossing bin
    for (int p = t; p < HW; p += 1024) {
        unsigned int pk = pk_b[p];
        unsigned char m = mt_b[p];
        if ((pk >> 16) == bs && (m & 4)) {
            unsigned int pos = atomicAdd(&cnt, 1u);
            if (pos < LISTCAP)
                list[pos] = ((unsigned long long)pk << 32) |
                            ((unsigned long long)p << 16) | (unsigned long long)m;
        }
    }
    __syncthreads();
    int n = (int)min(cnt, (unsigned int)LISTCAP);
    // bitonic sort ascending by (pkey, idx)
    int np = 1; while (np < n) np <<= 1;
    for (int i = n + t; i < np; i += 1024) list[i] = ~0ull;
    __syncthreads();
    for (int k = 2; k <= np; k <<= 1) {
        for (int j = k >> 1; j > 0; j >>= 1) {
            for (int i = t; i < np; i += 1024) {
                int ixj = i ^ j;
                if (ixj > i) {
                    unsigned long long a = list[i], c = list[ixj];
                    bool asc = ((i & k) == 0);
                    if ((a > c) == asc) { list[i] = c; list[ixj] = a; }
                }
            }
            __syncthreads();
        }
    }
    // exact greedy over the bin (sequential, ~n<=300 iterations)
    if (t == 0) {
        float usage = (float)wbefore[b];
        for (int i = 0; i < n; ++i) {
            unsigned long long v = list[i];
            int g = (int)(v & 3ull);
            float c = (float)(4 >> g);
            if (usage + c <= budget) {
                usage += c;
                int p = (int)((v >> 16) & 0xFFFFull);
                sel[(b << 16) | p]  = (float)g;
                sel8[(b << 16) | p] = (char)g;
            }
        }
        usage_sh = usage;
    }
    __syncthreads();
    // tail: at most 3 more accepts among bins > b*, in exact priority order
    float r = budget - usage_sh;
    unsigned long long lo = ((unsigned long long)(bs + 1)) << 32; // first comp of next bin
    for (int iter = 0; iter < 8; ++iter) {
        if (r < 1.0f) break;
        unsigned long long best = ~0ull;
        for (int p = t; p < HW; p += 1024) {
            unsigned char m = mt_b[p];
            if (m & 4) {
                int cost = 4 >> (m & 3);
                if ((float)cost <= r) {
                    unsigned long long c48 = ((unsigned long long)pk_b[p] << 16) |
                                             (unsigned long long)p;
                    if (c48 >= lo && c48 < best) best = c48;
                }
            }
        }
        red[t] = best; __syncthreads();
        for (int off = 512; off > 0; off >>= 1) {
            if (t < off) { if (red[t + off] < red[t]) red[t] = red[t + off]; }
            __syncthreads();
        }
        unsigned long long found = red[0];
        __syncthreads();
        if (found == ~0ull) break;
        int p = (int)(found & 0xFFFFull);
        unsigned char m = mt_b[p];
        int g = m & 3;
        if (t == 0) {
            sel[(b << 16) | p]  = (float)g;
            sel8[(b << 16) | p] = (char)g;
        }
        r -= (float)(4 >> g);
        lo = found + 1;
    }
}

// K5: masked copy of the big tensor. One thread = one float4 (4 W-pixels).
__global__ void k_mask(const float4* __restrict__ in,
                       const char* __restrict__ sel8,
                       float4* __restrict__ out) {
    const unsigned int TOT4 = (unsigned int)NB * NC * (HW / 4); // 20,971,520
    unsigned int stride = gridDim.x * blockDim.x;
    for (unsigned int i = blockIdx.x * blockDim.x + threadIdx.x; i < TOT4; i += stride) {
        unsigned int p4 = i & ((HW / 4) - 1);
        unsigned int bc = i >> 14;
        unsigned int c = bc & (NC - 1);
        unsigned int b = bc >> 8;
        int g = (c < 64) ? 0 : ((c < 192) ? 1 : 2);
        char4 s4 = *reinterpret_cast<const char4*>(sel8 + ((size_t)b << 16) + (p4 << 2));
        bool m0 = (int)s4.x == g, m1 = (int)s4.y == g,
             m2 = (int)s4.z == g, m3 = (int)s4.w == g;
        float4 v = make_float4(0.f, 0.f, 0.f, 0.f);
        if (m0 | m1 | m2 | m3) {       // skip the HBM read when nothing selected
            float4 x = in[i];
            v.x = m0 ? x.x : 0.f;
            v.y = m1 ? x.y : 0.f;
            v.z = m2 ? x.z : 0.f;
            v.w = m3 ? x.w : 0.f;
        }
        out[i] = v;
    }
}

extern "C" void kernel_launch(void* const* d_in, const int* in_sizes, int n_in,
                              void* d_out, int out_size, void* d_ws, size_t ws_size,
                              hipStream_t stream) {
    const float* collab = (const float*)d_in[0];   // (5,256,256,256) f32
    const float* util   = (const float*)d_in[1];   // (5,256,256,3)  f32
    const int*   budget = (const int*)d_in[2];     // scalar

    float* f_trans = (float*)d_out;                        // (5,256,65536)
    float* sel     = f_trans + (size_t)NB * NC * HW;       // (5,65536)

    char* ws = (char*)d_ws;
    unsigned int*  hist    = (unsigned int*)(ws + 0);          // 5*65536*4 = 1,310,720
    unsigned int*  pkeys   = (unsigned int*)(ws + 1310720);    // 1,310,720
    unsigned char* meta    = (unsigned char*)(ws + 2621440);   // 327,680
    char*          sel8    = (char*)(ws + 2949120);            // 327,680
    unsigned int*  bstar   = (unsigned int*)(ws + 3276800);    // 20
    unsigned int*  wbefore = (unsigned int*)(ws + 3276832);    // 20

    hipMemsetAsync(hist, 0, (size_t)NB * 65536 * 4, stream);
    k_prep<<<(NB * HW + 255) / 256, 256, 0, stream>>>(util, pkeys, meta, hist);
    k_scan<<<NB, 1024, 0, stream>>>(hist, budget, bstar, wbefore);
    k_selbase<<<(NB * HW + 255) / 256, 256, 0, stream>>>(pkeys, meta, bstar, sel, sel8);
    k_boundary<<<NB, 1024, 0, stream>>>(pkeys, meta, bstar, wbefore, budget, sel, sel8);
    k_mask<<<4096, 256, 0, stream>>>((const float4*)collab, sel8, (float4*)f_trans);
}

// Round 3
// 639.414 us; speedup vs baseline: 1.0023x; 1.0023x over previous
//
#include <hip/hip_runtime.h>

// Problem constants (fixed by reference setup_inputs)
#define NB 5            // B (cav_num)
#define HW 65536        // 256*256
#define NC 256          // C_V+C_F+C_D
#define LISTCAP 4096    // boundary-bin LDS list capacity (expected ~150-260 items)

typedef float v4f __attribute__((ext_vector_type(4)));

// Monotone key: ascending pkey == descending utility. Stable ties broken by pixel idx.
__device__ __forceinline__ unsigned int pkey_of(float u) {
    unsigned int b = __float_as_uint(u);
    unsigned int o = (b & 0x80000000u) ? ~b : (b | 0x80000000u); // ascending in u
    return ~o;                                                   // descending in u
}

__device__ __forceinline__ float budget_per_sample(const int* bp) {
    // Robust to harness passing int32/int64 (150000) or float32 (150000.0f) bits.
    int v = bp[0];
    float f = (v > 0 && v < 100000000) ? (float)v : __int_as_float(v);
    return f / (float)NB;   // 150000/5 = 30000.0 exact
}

// K1: per-pixel best utility/group, priority key, weighted cost histogram.
__global__ void k_prep(const float* __restrict__ util,
                       unsigned int* __restrict__ pkeys,
                       unsigned char* __restrict__ meta,
                       unsigned int* __restrict__ hist) {
    int i = blockIdx.x * blockDim.x + threadIdx.x;
    if (i >= NB * HW) return;
    int b = i >> 16;
    const float* u3 = util + (size_t)i * 3;
    float u0 = u3[0], u1 = u3[1], u2 = u3[2];
    int g = 0; float u = u0;
    if (u1 > u) { u = u1; g = 1; }   // jnp.argmax: first max wins (strict >)
    if (u2 > u) { u = u2; g = 2; }
    bool valid = u > 0.0f;           // PENALTY = 0
    unsigned int pk = pkey_of(u);
    pkeys[i] = pk;
    meta[i] = (unsigned char)(g | (valid ? 4 : 0));
    if (valid) {
        int cost = 4 >> g;           // COSTS = [4,2,1]
        atomicAdd(&hist[(b << 16) | (pk >> 16)], (unsigned int)cost);
    }
}

// K2 (fused): per-sample weighted-bin scan -> (b*, W<) in LDS; phase-1 base
// selection for all pixels; exact resolve of the crossing bin via LDS bitonic
// sort + sequential greedy; tail (<=3 extra accepts) via iterative argmin.
// One 1024-thread block per sample.
__global__ void __launch_bounds__(1024) k_select(const unsigned int* __restrict__ pkeys,
                                                 const unsigned char* __restrict__ meta,
                                                 const unsigned int* __restrict__ hist,
                                                 const int* __restrict__ budget_ptr,
                                                 float* __restrict__ sel,
                                                 char* __restrict__ sel8) {
    int b = blockIdx.x;
    int t = threadIdx.x;
    float budget = budget_per_sample(budget_ptr);

    __shared__ unsigned int ls[1024];
    __shared__ unsigned int s_bstar, s_wbefore;
    __shared__ unsigned long long list[LISTCAP];
    __shared__ unsigned long long red[1024];
    __shared__ unsigned int cnt;
    __shared__ float usage_sh;

    // ---- scan: find crossing bin ----
    const unsigned int* h = hist + (b << 16);
    unsigned int s = 0;
    #pragma unroll 4
    for (int j = 0; j < 64; ++j) s += h[t * 64 + j];
    ls[t] = s; __syncthreads();
    for (int off = 1; off < 1024; off <<= 1) {       // Hillis-Steele inclusive scan
        unsigned int v = (t >= off) ? ls[t - off] : 0u;
        __syncthreads();
        ls[t] += v;
        __syncthreads();
    }
    unsigned int incl = ls[t];
    unsigned int excl = incl - s;
    if ((float)excl <= budget && (float)incl > budget) {   // unique crossing thread
        unsigned int cum = excl; int bb = t * 64;
        for (int j = 0; j < 64; ++j) {
            unsigned int nc = cum + h[t * 64 + j];
            if ((float)nc > budget) { bb = t * 64 + j; break; }
            cum = nc;
        }
        s_bstar = (unsigned int)bb;
        s_wbefore = cum;
    }
    if (t == 1023 && (float)incl <= budget) {        // budget never exceeded
        s_bstar = 65536u;
        s_wbefore = incl;
    }
    if (t == 0) cnt = 0;
    __syncthreads();
    unsigned int bs = s_bstar;

    // ---- phase-1 base selection for this sample ----
    const unsigned int* pk_b = pkeys + (b << 16);
    const unsigned char* mt_b = meta + (b << 16);
    float* sel_b = sel + (b << 16);
    char* sel8_b = sel8 + (b << 16);
    for (int p = t; p < HW; p += 1024) {
        unsigned int pk = pk_b[p];
        unsigned char m = mt_b[p];
        bool acc = ((pk >> 16) < bs) && (m & 4);
        sel_b[p]  = acc ? (float)(m & 3) : -1.0f;
        sel8_b[p] = acc ? (char)(m & 3) : (char)-1;
        if (acc == false && (pk >> 16) == bs && (m & 4)) {
            unsigned int pos = atomicAdd(&cnt, 1u);   // gather crossing-bin items
            if (pos < LISTCAP)
                list[pos] = ((unsigned long long)pk << 32) |
                            ((unsigned long long)p << 16) | (unsigned long long)m;
        }
    }
    if (bs >= 65536u) return;                         // uniform: no crossing
    __syncthreads();

    // ---- bitonic sort of the crossing bin, ascending (pkey, idx) ----
    int n = (int)min(cnt, (unsigned int)LISTCAP);
    int np = 1; while (np < n) np <<= 1;
    for (int i = n + t; i < np; i += 1024) list[i] = ~0ull;
    __syncthreads();
    for (int k = 2; k <= np; k <<= 1) {
        for (int j = k >> 1; j > 0; j >>= 1) {
            for (int i = t; i < np; i += 1024) {
                int ixj = i ^ j;
                if (ixj > i) {
                    unsigned long long a = list[i], c = list[ixj];
                    bool asc = ((i & k) == 0);
                    if ((a > c) == asc) { list[i] = c; list[ixj] = a; }
                }
            }
            __syncthreads();
        }
    }

    // ---- exact greedy over the bin (sequential, n ~ 150-300) ----
    if (t == 0) {
        float usage = (float)s_wbefore;
        for (int i = 0; i < n; ++i) {
            unsigned long long v = list[i];
            int g = (int)(v & 3ull);
            float c = (float)(4 >> g);
            if (usage + c <= budget) {
                usage += c;
                int p = (int)((v >> 16) & 0xFFFFull);
                sel_b[p]  = (float)g;
                sel8_b[p] = (char)g;
            }
        }
        usage_sh = usage;
    }
    __syncthreads();

    // ---- tail: at most 3 more accepts among bins > b*, in exact order ----
    float r = budget - usage_sh;                      // r < 4 guaranteed
    unsigned long long lo = ((unsigned long long)(bs + 1)) << 32;
    for (int iter = 0; iter < 8; ++iter) {
        if (r < 1.0f) break;
        unsigned long long best = ~0ull;
        for (int p = t; p < HW; p += 1024) {
            unsigned char m = mt_b[p];
            if (m & 4) {
                int cost = 4 >> (m & 3);
                if ((float)cost <= r) {
                    unsigned long long c48 = ((unsigned long long)pk_b[p] << 16) |
                                             (unsigned long long)p;
                    if (c48 >= lo && c48 < best) best = c48;
                }
            }
        }
        red[t] = best; __syncthreads();
        for (int off = 512; off > 0; off >>= 1) {
            if (t < off) { if (red[t + off] < red[t]) red[t] = red[t + off]; }
            __syncthreads();
        }
        unsigned long long found = red[0];
        __syncthreads();
        if (found == ~0ull) break;
        int p = (int)(found & 0xFFFFull);
        unsigned char m = mt_b[p];
        int g = m & 3;
        if (t == 0) {
            sel_b[p]  = (float)g;
            sel8_b[p] = (char)g;
        }
        r -= (float)(4 >> g);
        lo = found + 1;
    }
}

// K3: masked copy. One block per (b,c) plane: group/base computed once,
// 64 KB sel slice L2-resident, nontemporal streaming for the 336 MB tensor.
__global__ void __launch_bounds__(256) k_mask(const v4f* __restrict__ in,
                                              const unsigned int* __restrict__ sel32,
                                              v4f* __restrict__ out) {
    int bc = blockIdx.x;                    // 0..NB*NC-1
    int b  = bc >> 8;
    int c  = bc & 255;
    unsigned int g = (c < 64) ? 0u : ((c < 192) ? 1u : 2u);
    const unsigned int* sp = sel32 + (b << 14);          // HW/4 packed sel bytes
    const v4f* ip = in  + (size_t)bc * (HW / 4);
    v4f*       op = out + (size_t)bc * (HW / 4);
    for (int p4 = threadIdx.x; p4 < HW / 4; p4 += 256) {
        unsigned int s = sp[p4];
        bool m0 = ((s        & 0xffu) == g);
        bool m1 = (((s >> 8) & 0xffu) == g);
        bool m2 = (((s >> 16)& 0xffu) == g);
        bool m3 = ((s >> 24)          == g);
        v4f v = {0.f, 0.f, 0.f, 0.f};
        if (m0 | m1 | m2 | m3) {            // skip HBM read when nothing selected
            v4f x = __builtin_nontemporal_load(ip + p4);
            v.x = m0 ? x.x : 0.f;
            v.y = m1 ? x.y : 0.f;
            v.z = m2 ? x.z : 0.f;
            v.w = m3 ? x.w : 0.f;
        }
        __builtin_nontemporal_store(v, op + p4);
    }
}

extern "C" void kernel_launch(void* const* d_in, const int* in_sizes, int n_in,
                              void* d_out, int out_size, void* d_ws, size_t ws_size,
                              hipStream_t stream) {
    const float* collab = (const float*)d_in[0];   // (5,256,256,256) f32
    const float* util   = (const float*)d_in[1];   // (5,256,256,3)  f32
    const int*   budget = (const int*)d_in[2];     // scalar

    float* f_trans = (float*)d_out;                        // (5,256,65536)
    float* sel     = f_trans + (size_t)NB * NC * HW;       // (5,65536)

    char* ws = (char*)d_ws;
    unsigned int*  hist  = (unsigned int*)(ws + 0);          // 5*65536*4 = 1,310,720 B
    unsigned int*  pkeys = (unsigned int*)(ws + 1310720);    // 1,310,720 B
    unsigned char* meta  = (unsigned char*)(ws + 2621440);   // 327,680 B
    char*          sel8  = (char*)(ws + 2949120);            // 327,680 B (4-aligned)

    hipMemsetAsync(hist, 0, (size_t)NB * 65536 * 4, stream);
    k_prep<<<(NB * HW + 255) / 256, 256, 0, stream>>>(util, pkeys, meta, hist);
    k_select<<<NB, 1024, 0, stream>>>(pkeys, meta, hist, budget, sel, sel8);
    k_mask<<<NB * NC, 256, 0, stream>>>((const v4f*)collab,
                                        (const unsigned int*)sel8, (v4f*)f_trans);
}